// Round 14
// baseline (3919.799 us; speedup 1.0000x reference)
//
#include <hip/hip_runtime.h>
#include <hip/hip_bf16.h>

#define N_EDGES_C 1000000
#define EDGE_DIM_C 64
#define NODE_DIM_C 64
#define IN_DIM_C   192
#define HID_C      256
#define N_TILES    62500      // 16-edge wave-tiles
#define GRID_BLKS  512

typedef __attribute__((ext_vector_type(8))) short  short8;
typedef __attribute__((ext_vector_type(4))) float  f32x4;

__device__ __forceinline__ unsigned short f2bf(float f) {
    union { float f; unsigned u; } v; v.f = f;
    unsigned u = v.u;
    u += 0x7fffu + ((u >> 16) & 1u);   // round-to-nearest-even
    return (unsigned short)(u >> 16);
}

// sigma: acc1 slot r = nt*16 + lg*4 + j  ->  original feature
//        f = (nt>>1)*32 + lg*8 + (nt&1)*4 + j
// With W1 rows permuted by sigma, lane-local acc1 slots pack directly into
// the L2 B-fragment (8 consecutive k per kb) -- H never leaves registers.
// (Verified numerically in R12: passed absmax.)
__device__ __forceinline__ int sigma_feat(int r) {
    return ((r >> 5) << 5) | (((r >> 2) & 3) << 3) | (((r >> 4) & 1) << 2) | (r & 3);
}

__global__ void prep_weights_kernel(const float* __restrict__ W1,
                                    const float* __restrict__ W2,
                                    const float* __restrict__ b1,
                                    unsigned short* __restrict__ W1Tn,
                                    unsigned short* __restrict__ W2T,
                                    float* __restrict__ b1p) {
    int tid = blockIdx.x * 256 + threadIdx.x;
    if (tid < IN_DIM_C * HID_C) {                        // 49152
        int r = tid / IN_DIM_C, k = tid - r * IN_DIM_C;
        W1Tn[tid] = f2bf(W1[k * HID_C + sigma_feat(r)]);
    } else if (tid < IN_DIM_C * HID_C + HID_C * HID_C) { // +65536
        int t2 = tid - IN_DIM_C * HID_C;
        int o = t2 >> 8, k = t2 & 255;
        W2T[t2] = f2bf(W2[k * HID_C + o]);
    } else if (tid < IN_DIM_C * HID_C + HID_C * HID_C + HID_C) {
        int r = tid - IN_DIM_C * HID_C - HID_C * HID_C;
        b1p[r] = b1[sigma_feat(r)];
    }
}

// 512 threads = 8 INDEPENDENT waves (one __syncthreads after W2->LDS staging,
// then zero barriers). Wave-tile = 16 edges; each wave computes ALL 256
// output features for its edges, grid-striding on its own schedule:
//   X: 12 f32x4 global->reg in B-frag layout (E via NT load, V gather)
//   L1: A = W1Tn streamed from L2 (96KB, hot), B = xf  -> acc1 (sigma'd)
//   H: bias+relu+cvt lane-local (sigma trick), zero cross-lane movement
//   L2: A = W2 from LDS (XOR-swizzled, staged once),  B = hf -> acc2
//   store: 16 NT f32x4 covering the full 1KB row per edge (merge-friendly)
// This is the first structure where waves are phase-DECORRELATED: wave A's
// HBM wait overlaps wave B's MFMA/LDS on the same SIMD (m114 mechanism).
__global__ __launch_bounds__(512, 2) void edge_mlp_kernel(
    const float* __restrict__ E, const float* __restrict__ V,
    const int* __restrict__ srcI, const int* __restrict__ dstI,
    const unsigned short* __restrict__ W1Tn, const float* __restrict__ b1p,
    const unsigned short* __restrict__ W2T, const float* __restrict__ b2,
    float* __restrict__ out)
{
    __shared__ unsigned char w2s[131072];   // W2 bf16 [256][256], swizzled
    const int tid = threadIdx.x;

    // ---- stage W2 -> LDS once: row r, 16B chunk cb at r*512 + (cb^((r&7)<<4)) ----
#pragma unroll
    for (int i = 0; i < 16; ++i) {
        int c  = tid + i * 512;             // 16B-chunk id 0..8191
        int r  = c >> 5;
        int cb = (c & 31) << 4;
        short8 v = *reinterpret_cast<const short8*>(W2T + (size_t)c * 8);
        *reinterpret_cast<short8*>(w2s + r * 512 + (cb ^ ((r & 7) << 4))) = v;
    }
    __syncthreads();                        // the ONLY block-wide barrier

    const int l    = tid & 63;
    const int lm   = l & 15;
    const int lg   = l >> 4;
    const int col8 = lg * 8;
    const int swz  = (lm & 7) << 4;
    const int gw   = blockIdx.x * 8 + (tid >> 6);
    const int nw   = GRID_BLKS * 8;

    for (int tile = gw; tile < N_TILES; tile += nw) {
        const long eb = (long)tile * 16;

        // ---- gather indices (coalesced 16-wide, lane-redundant over lg) ----
        int si = srcI[eb + lm];
        int di = dstI[eb + lm];

        // ---- X frags: direct global -> reg (B-frag layout) ----
        short8 xf[6];
        {
            const float* ep = E + (size_t)(eb + lm) * EDGE_DIM_C;
            const float* vs = V + (size_t)si * NODE_DIM_C;
            const float* vd = V + (size_t)di * NODE_DIM_C;
#pragma unroll
            for (int kb = 0; kb < 6; ++kb) {
                f32x4 a, b;
                if (kb < 2) {        // E features: stream-once, NT
                    a = __builtin_nontemporal_load(
                        reinterpret_cast<const f32x4*>(ep + kb * 32 + col8));
                    b = __builtin_nontemporal_load(
                        reinterpret_cast<const f32x4*>(ep + kb * 32 + col8 + 4));
                } else if (kb < 4) { // V[src]: cacheable
                    a = *reinterpret_cast<const f32x4*>(vs + (kb - 2) * 32 + col8);
                    b = *reinterpret_cast<const f32x4*>(vs + (kb - 2) * 32 + col8 + 4);
                } else {             // V[dst]
                    a = *reinterpret_cast<const f32x4*>(vd + (kb - 4) * 32 + col8);
                    b = *reinterpret_cast<const f32x4*>(vd + (kb - 4) * 32 + col8 + 4);
                }
                short8 t;
                t[0] = f2bf(a[0]); t[1] = f2bf(a[1]); t[2] = f2bf(a[2]); t[3] = f2bf(a[3]);
                t[4] = f2bf(b[0]); t[5] = f2bf(b[1]); t[6] = f2bf(b[2]); t[7] = f2bf(b[3]);
                xf[kb] = t;
            }
        }

        // ---- Layer 1: A = W1Tn (L2-hot), B = xf -> acc1[16] ----
        f32x4 acc1[16];
#pragma unroll
        for (int n = 0; n < 16; ++n) acc1[n] = (f32x4){0.f, 0.f, 0.f, 0.f};

#pragma unroll
        for (int kb = 0; kb < 6; ++kb) {
#pragma unroll
            for (int h = 0; h < 4; ++h) {   // 4 blocks of 4 rows: aw[4]=16 regs
                short8 aw[4];
#pragma unroll
                for (int o = 0; o < 4; ++o)
                    aw[o] = *reinterpret_cast<const short8*>(
                        W1Tn + (size_t)((h * 4 + o) * 16 + lm) * IN_DIM_C + kb * 32 + col8);
#pragma unroll
                for (int o = 0; o < 4; ++o)
                    acc1[h * 4 + o] = __builtin_amdgcn_mfma_f32_16x16x32_bf16(
                        aw[o], xf[kb], acc1[h * 4 + o], 0, 0, 0);
            }
        }

        // ---- H: bias + relu + cvt, fully lane-local (sigma trick) ----
        short8 hf[8];
#pragma unroll
        for (int nt = 0; nt < 16; ++nt) {
            f32x4 bb = *reinterpret_cast<const f32x4*>(b1p + nt * 16 + lg * 4);
#pragma unroll
            for (int j = 0; j < 4; ++j)
                hf[nt >> 1][(nt & 1) * 4 + j] =
                    (short)f2bf(fmaxf(acc1[nt][j] + bb[j], 0.f));
        }

        // ---- Layer 2: A = W2 (LDS, swizzled), B = hf -> acc2[16] ----
        f32x4 acc2[16];
#pragma unroll
        for (int n = 0; n < 16; ++n) acc2[n] = (f32x4){0.f, 0.f, 0.f, 0.f};

#pragma unroll
        for (int kb = 0; kb < 8; ++kb) {
#pragma unroll
            for (int h = 0; h < 4; ++h) {
                short8 aw[4];
#pragma unroll
                for (int o = 0; o < 4; ++o) {
                    int ot = h * 4 + o;
                    aw[o] = *reinterpret_cast<const short8*>(
                        w2s + (ot * 16 + lm) * 512 + ((kb * 64 + lg * 16) ^ swz));
                }
#pragma unroll
                for (int o = 0; o < 4; ++o)
                    acc2[h * 4 + o] = __builtin_amdgcn_mfma_f32_16x16x32_bf16(
                        aw[o], hf[kb], acc2[h * 4 + o], 0, 0, 0);
            }
        }

        // ---- store: +b2, NT f32x4; each wave covers full 1KB rows ----
#pragma unroll
        for (int ot = 0; ot < 16; ++ot) {
            f32x4 bb = *reinterpret_cast<const f32x4*>(b2 + ot * 16 + lg * 4);
            f32x4 r = acc2[ot] + bb;
            __builtin_nontemporal_store(r, reinterpret_cast<f32x4*>(
                out + (size_t)(eb + lm) * HID_C + ot * 16 + lg * 4));
        }
    }
}

extern "C" void kernel_launch(void* const* d_in, const int* in_sizes, int n_in,
                              void* d_out, int out_size, void* d_ws, size_t ws_size,
                              hipStream_t stream) {
    const float* E  = (const float*)d_in[0];
    const float* V  = (const float*)d_in[1];
    const int*   ei = (const int*)d_in[2];   // [2][N_EDGES] int32
    const float* W1 = (const float*)d_in[3];
    const float* b1 = (const float*)d_in[4];
    const float* W2 = (const float*)d_in[5];
    const float* b2 = (const float*)d_in[6];
    float* out = (float*)d_out;

    unsigned short* W1Tn = (unsigned short*)d_ws;                  // 49152 bf16
    unsigned short* W2T  = W1Tn + IN_DIM_C * HID_C;                // 65536 bf16
    float*          b1p  = (float*)(W2T + HID_C * HID_C);          // 256 f32

    const int prep_total = IN_DIM_C * HID_C + HID_C * HID_C + HID_C; // 114944
    prep_weights_kernel<<<(prep_total + 255) / 256, 256, 0, stream>>>(
        W1, W2, b1, W1Tn, W2T, b1p);

    edge_mlp_kernel<<<GRID_BLKS, 512, 0, stream>>>(
        E, V, ei, ei + N_EDGES_C, W1Tn, b1p, W2T, b2, out);
}